// Round 9
// baseline (353.208 us; speedup 1.0000x reference)
//
#include <hip/hip_runtime.h>

#define NROW 16384
#define ROWI 10246
#define NSLICE 6                  // 0=G, 1=D, 2=A(q0), 3..5=A(q1..q3)
#define POUT_F (NSLICE*33*16384)
#define NSLOT 323                 // B slots: 0..319 tiles, 321=D@t0, 322=A@t69
#define BF_U16 ((size_t)NSLOT*128*8)
#define BITS_W 320                // u32 words per row: 10240 cols / 32
#define BITS_U32 ((size_t)NROW*BITS_W)
#define PTAB_ROWS 3438
#define PTAB_F (PTAB_ROWS*64)

typedef unsigned int u32;
typedef unsigned long long u64;
typedef unsigned short u16;
typedef short short8 __attribute__((ext_vector_type(8)));
typedef float f32x4 __attribute__((ext_vector_type(4)));

union AFrag { u32 u[4]; short8 s; };
union BFrag { uint4 v; short8 s; };

// ---------------- prep: B fragment table (bf16, MFMA layout) ----------------
// Frag id = (slot*2 + f)*64 + lane ; elem e: k = t*32 + (lane>>4)*8 + e,
// d = f*16 + (lane&15). Masked to the slot's segment (zeros elsewhere).
__global__ void prep_bf(const float* __restrict__ Wg, const float* __restrict__ Wd,
                        const float* __restrict__ Wa, u16* __restrict__ Bf) {
  int id = blockIdx.x*256 + threadIdx.x;
  if (id >= NSLOT*128) return;
  int lane = id & 63, f = (id >> 6) & 1, slot = id >> 7;
  int t   = (slot == 321) ? 0 : (slot == 322) ? 69 : slot;
  int seg = (slot == 0) ? 0 : (slot <= 69) ? 1 : (slot <= 320) ? 2
            : (slot == 321) ? 1 : 2;                  // 0=G,1=D,2=A
  int clo = (seg == 0) ? 1  : (seg == 1) ? 26   : 2212;
  int chi = (seg == 0) ? 26 : (seg == 1) ? 2212 : 10242;
  int d  = f*16 + (lane & 15);
  int kb = t*32 + (lane >> 4)*8;
  u16 o[8];
  #pragma unroll
  for (int e = 0; e < 8; ++e) {
    int c = kb + e;
    float v = 0.f;
    if (c >= clo && c < chi) {
      if (seg == 0)      v = Wg[d*25   + (c-1)];
      else if (seg == 1) v = Wd[d*2186 + (c-26)];
      else               v = Wa[d*8030 + (c-2212)];
    }
    u32 bits = __float_as_uint(v);                    // RNE float->bf16
    o[e] = (u16)((bits + 0x7FFFu + ((bits >> 16) & 1u)) >> 16);
  }
  uint4 w;
  w.x = (u32)o[0] | ((u32)o[1] << 16);
  w.y = (u32)o[2] | ((u32)o[3] << 16);
  w.z = (u32)o[4] | ((u32)o[5] << 16);
  w.w = (u32)o[6] | ((u32)o[7] << 16);
  *(uint4*)&Bf[(size_t)id*8] = w;
}

// ---------------- prep: folded index-embedding table ----------------
__global__ void prep_p(const float* __restrict__ er, const float* __restrict__ eg,
                       const float* __restrict__ ea, const float* __restrict__ eo,
                       const float* __restrict__ ez, const float* __restrict__ W1,
                       float* __restrict__ P) {
  int id = blockIdx.x*256 + threadIdx.x;
  if (id >= PTAB_F) return;
  int r = id >> 6, o = id & 63;
  const float* emb; int woff;
  if (r < 6)       { emb = er + r*32;       woff = 0;   }
  else if (r < 8)  { emb = eg + (r-6)*32;   woff = 128; }
  else if (r < 15) { emb = ea + (r-8)*32;   woff = 160; }
  else if (r < 36) { emb = eo + (r-15)*32;  woff = 192; }
  else             { emb = ez + (r-36)*32;  woff = 224; }
  const float* w = W1 + o*256 + woff;
  float s = 0.f;
  #pragma unroll
  for (int c2 = 0; c2 < 32; ++c2) s += emb[c2]*w[c2];
  P[id] = s;
}

__global__ void prep_w2t(const float* __restrict__ W2, float* __restrict__ W2t) {
  int id = blockIdx.x*256 + threadIdx.x;
  if (id >= 64*64) return;
  int o = id >> 6, o2 = id & 63;
  W2t[o*64 + o2] = W2[o2*64 + o];
}

// ---------------- pack: linear-stream x -> bit matrix ----------------
// Wave = one row. Group g covers cols [2048g, 2048g+2048) -> words [64g, 64g+64).
// Word w bit j = x[row][32w + j]. 16-deep load batches for MLP.
__global__ __launch_bounds__(256) void pack(const int* __restrict__ x,
                                            u32* __restrict__ bits) {
  const int lane = threadIdx.x & 63;
  const int row  = blockIdx.x*4 + (threadIdx.x >> 6);
  const int* base = x + (size_t)row*ROWI;
  u32* obase = bits + (size_t)row*BITS_W;
  #pragma unroll
  for (int g = 0; g < 5; ++g) {
    u32 keep = 0;
    #pragma unroll
    for (int ib = 0; ib < 2; ++ib) {
      int v[16];
      #pragma unroll
      for (int k = 0; k < 16; ++k)
        v[k] = base[g*2048 + (ib*16 + k)*64 + lane];
      #pragma unroll
      for (int k = 0; k < 16; ++k) {
        const int i = ib*16 + k;
        const u64 b = __ballot(v[k] != 0);
        keep = (lane == 2*i)     ? (u32)b         : keep;
        keep = (lane == 2*i + 1) ? (u32)(b >> 32) : keep;
      }
    }
    obase[g*64 + lane] = keep;     // coalesced: words 64g..64g+63
  }
}

// ---------------- fused MFMA bag kernel (A from bit matrix) ----------------
// Wave = 32 rows (2 row-sets of 16); block = 4 waves = 128 rows; blockIdx.y = q (K quarter).
// A: row = lane&15, k = (lane>>4)*8+e.  D: d = lane&15, row = (lane>>4)*4+reg.
__global__ __launch_bounds__(256, 2) void kmain(
    const u32* __restrict__ bits, const u16* __restrict__ Bf, float* __restrict__ pout) {
  const int lane = threadIdx.x & 63;
  const int wv   = threadIdx.x >> 6;
  const int q    = blockIdx.y;
  const bool q0  = (q == 0);
  const int row0w = blockIdx.x*128 + wv*32;
  const int r = lane & 15, g = lane >> 4, g8 = g*8;

  const int tb = q*80, tmax = tb + 79;

  const u32*   pW0 = bits + (size_t)(row0w + r)*BITS_W;
  const u32*   pW1 = bits + (size_t)(row0w + 16 + r)*BITS_W;
  const uint4* pB  = (const uint4*)Bf + lane;          // + (t*2+f)*64

  f32x4 z = {0.f,0.f,0.f,0.f};
  f32x4 G00=z,G01=z,G10=z,G11=z, D00=z,D01=z,D10=z,D11=z, A00=z,A01=z,A10=z,A11=z;
  int cG0=0,cG1=0,cD0=0,cD1=0,cA0=0,cA1=0;

  u32 wE0, wE1, wO0, wO1;
  uint4 bE0, bE1, bO0, bO1;
  wE0 = pW0[tb];   wE1 = pW1[tb];
  wO0 = pW0[tb+1]; wO1 = pW1[tb+1];
  bE0 = pB[(tb*2)*64];     bE1 = pB[(tb*2+1)*64];
  bO0 = pB[((tb+1)*2)*64]; bO1 = pB[((tb+1)*2+1)*64];

#define BUILD_AF(AF, BYTE)                                                      \
    AF.u[0] = __umul24(((BYTE)      & 1u) + ((((BYTE) >> 1) & 1u) << 16), 0x3F80u); \
    AF.u[1] = __umul24((((BYTE)>>2) & 1u) + ((((BYTE) >> 3) & 1u) << 16), 0x3F80u); \
    AF.u[2] = __umul24((((BYTE)>>4) & 1u) + ((((BYTE) >> 5) & 1u) << 16), 0x3F80u); \
    AF.u[3] = __umul24((((BYTE)>>6) & 1u) + ((((BYTE) >> 7) & 1u) << 16), 0x3F80u);

#define MFMA4(P, B0, B1, AF0, AF1)                                             \
    P##00 = __builtin_amdgcn_mfma_f32_16x16x32_bf16(AF0.s, B0.s, P##00,0,0,0); \
    P##01 = __builtin_amdgcn_mfma_f32_16x16x32_bf16(AF0.s, B1.s, P##01,0,0,0); \
    P##10 = __builtin_amdgcn_mfma_f32_16x16x32_bf16(AF1.s, B0.s, P##10,0,0,0); \
    P##11 = __builtin_amdgcn_mfma_f32_16x16x32_bf16(AF1.s, B1.s, P##11,0,0,0);

#define PH(S, TT) do {                                                         \
    const int tt = (TT);                                                       \
    const u32 by0 = (w##S##0 >> g8) & 0xFFu;                                   \
    const u32 by1 = (w##S##1 >> g8) & 0xFFu;                                   \
    AFrag a0, a1; BUILD_AF(a0, by0); BUILD_AF(a1, by1);                        \
    BFrag b0, b1; b0.v = b##S##0; b1.v = b##S##1;                              \
    if (!q0) {                                                                 \
      MFMA4(A, b0, b1, a0, a1); cA0 += __popc(by0); cA1 += __popc(by1);        \
    } else if (tt == 0) {                                                      \
      MFMA4(G, b0, b1, a0, a1);                                                \
      BFrag e0, e1; e0.v = pB[(321*2)*64]; e1.v = pB[(321*2+1)*64];            \
      MFMA4(D, e0, e1, a0, a1);                                                \
      _Pragma("unroll")                                                        \
      for (int j = 0; j < 4; ++j) {                                            \
        const int c0 = g8 + 2*j, c1 = c0 + 1;                                  \
        const int u0 = (by0>>(2*j))&1, u1 = (by0>>(2*j+1))&1;                  \
        const int v0 = (by1>>(2*j))&1, v1 = (by1>>(2*j+1))&1;                  \
        if (c0 >= 1 && c0 < 26) { cG0 += u0; cG1 += v0; }                      \
        else if (c0 >= 26)      { cD0 += u0; cD1 += v0; }                      \
        if (c1 < 26) { cG0 += u1; cG1 += v1; } else { cD0 += u1; cD1 += v1; }  \
      }                                                                        \
    } else if (tt == 69) {                                                     \
      MFMA4(D, b0, b1, a0, a1);                                                \
      BFrag e0, e1; e0.v = pB[(322*2)*64]; e1.v = pB[(322*2+1)*64];            \
      MFMA4(A, e0, e1, a0, a1);                                                \
      _Pragma("unroll")                                                        \
      for (int j = 0; j < 4; ++j) {                                            \
        const int s0 = ((by0>>(2*j))&1) + ((by0>>(2*j+1))&1);                  \
        const int s1 = ((by1>>(2*j))&1) + ((by1>>(2*j+1))&1);                  \
        if (j < 2) { if (g == 0) { cD0 += s0; cD1 += s1; }                     \
                     else        { cA0 += s0; cA1 += s1; } }                   \
        else       { cA0 += s0; cA1 += s1; }                                   \
      }                                                                        \
    } else if (tt < 69) {                                                      \
      MFMA4(D, b0, b1, a0, a1); cD0 += __popc(by0); cD1 += __popc(by1);        \
    } else {                                                                   \
      MFMA4(A, b0, b1, a0, a1); cA0 += __popc(by0); cA1 += __popc(by1);        \
    }                                                                          \
    int tn = tt + 2; if (tn > tmax) tn = tmax;                                 \
    w##S##0 = pW0[tn]; w##S##1 = pW1[tn];                                      \
    b##S##0 = pB[(tn*2)*64]; b##S##1 = pB[(tn*2+1)*64];                        \
  } while (0)

  for (int i = 0; i < 40; ++i) {
    PH(E, tb + 2*i);
    PH(O, tb + 2*i + 1);
  }

  // per-row counts: reduce over the 4 k-groups (lanes l, l^16, l^32, l^48)
  cG0 += __shfl_xor(cG0,16); cG0 += __shfl_xor(cG0,32);
  cG1 += __shfl_xor(cG1,16); cG1 += __shfl_xor(cG1,32);
  cD0 += __shfl_xor(cD0,16); cD0 += __shfl_xor(cD0,32);
  cD1 += __shfl_xor(cD1,16); cD1 += __shfl_xor(cD1,32);
  cA0 += __shfl_xor(cA0,16); cA0 += __shfl_xor(cA0,32);
  cA1 += __shfl_xor(cA1,16); cA1 += __shfl_xor(cA1,32);

#define STO4(P, SL) do { float* bp = pout + (size_t)(SL)*33*16384;             \
    _Pragma("unroll")                                                          \
    for (int q2 = 0; q2 < 4; ++q2) {                                           \
      bp[(size_t)r*16384      + row0w + g*4 + q2]      = P##00[q2];            \
      bp[(size_t)(16+r)*16384 + row0w + g*4 + q2]      = P##01[q2];            \
      bp[(size_t)r*16384      + row0w + 16 + g*4 + q2] = P##10[q2];            \
      bp[(size_t)(16+r)*16384 + row0w + 16 + g*4 + q2] = P##11[q2];            \
    } } while (0)
#define STOC(SL, C0, C1) do { if (lane < 16) {                                 \
    pout[((size_t)(SL)*33 + 32)*16384 + row0w + lane]      = (float)(C0);      \
    pout[((size_t)(SL)*33 + 32)*16384 + row0w + 16 + lane] = (float)(C1); } } while (0)

  if (q0) {
    STO4(G, 0); STO4(D, 1); STO4(A, 2);
    STOC(0, cG0, cG1); STOC(1, cD0, cD1); STOC(2, cA0, cA1);
  } else {
    STO4(A, 2 + q);
    STOC(2 + q, cA0, cA1);
  }
#undef STO4
#undef STOC
#undef PH
#undef MFMA4
#undef BUILD_AF
}

// ---------------- reduce + tail + MLP kernel ----------------
__global__ __launch_bounds__(64, 1) void k2(
    const int* __restrict__ x, const float* __restrict__ pout,
    const float* __restrict__ Wa, const float* __restrict__ P,
    const float* __restrict__ W1, const float* __restrict__ b1,
    const float* __restrict__ W2t, const float* __restrict__ b2,
    const float* __restrict__ Wout, const float* __restrict__ bout,
    float* __restrict__ out) {
  const int row = blockIdx.x*64 + threadIdx.x;
  const int* xr = x + (size_t)row*ROWI;

#define PSL(SL, D) pout[(size_t)((SL)*33 + (D))*16384 + row]
  float mG[32], mD[32], mA[32];
  #pragma unroll
  for (int d = 0; d < 32; ++d) {
    mG[d] = PSL(0, d);
    mD[d] = PSL(1, d);
    mA[d] = (PSL(2, d) + PSL(3, d)) + (PSL(4, d) + PSL(5, d));
  }
  float cG = PSL(0, 32);
  float cD = PSL(1, 32);
  float cA = (PSL(2, 32) + PSL(3, 32)) + (PSL(4, 32) + PSL(5, 32));
#undef PSL

  // tail actor columns 10240, 10241 (= Wa cols 8028, 8029)
  {
    const float t0 = (float)xr[10240], t1 = (float)xr[10241];
    cA += t0 + t1;
    #pragma unroll
    for (int d = 0; d < 32; ++d)
      mA[d] = fmaf(t1, Wa[d*8030 + 8029], fmaf(t0, Wa[d*8030 + 8028], mA[d]));
  }

  #pragma unroll
  for (int d = 0; d < 32; ++d) { mG[d] /= cG; mD[d] /= cD; mA[d] /= cA; }

  const int ridx = xr[0];
  const int gi = xr[10242], ai = xr[10243], oi = xr[10244], ari = xr[10245];
  const float* Pr = P + (size_t)ridx*64;
  const float* Pg = P + (size_t)(6 + gi)*64;
  const float* Pa = P + (size_t)(8 + ai)*64;
  const float* Po = P + (size_t)(15 + oi)*64;
  const float* Pz = P + (size_t)(36 + ari)*64;

  float h1[64];
  #pragma unroll
  for (int o = 0; o < 64; ++o)
    h1[o] = b1[o] + ((Pr[o] + Pg[o]) + (Pa[o] + Po[o])) + Pz[o];

  #pragma unroll
  for (int o = 0; o < 64; ++o) {
    const float* w = W1 + o*256;
    float a = h1[o];
    #pragma unroll
    for (int d = 0; d < 32; ++d) a = fmaf(mG[d], w[32+d], a);
    #pragma unroll
    for (int d = 0; d < 32; ++d) a = fmaf(mD[d], w[64+d], a);
    #pragma unroll
    for (int d = 0; d < 32; ++d) a = fmaf(mA[d], w[96+d], a);
    h1[o] = fmaxf(a, 0.f);
  }

  float h2[64];
  #pragma unroll
  for (int o2 = 0; o2 < 64; ++o2) h2[o2] = b2[o2];
  #pragma unroll
  for (int o = 0; o < 64; ++o) {
    const float h = h1[o];
    const float* wr = W2t + o*64;
    #pragma unroll
    for (int o2 = 0; o2 < 64; ++o2) h2[o2] = fmaf(h, wr[o2], h2[o2]);
  }
  float acc = bout[0];
  #pragma unroll
  for (int o2 = 0; o2 < 64; ++o2) acc = fmaf(fmaxf(h2[o2], 0.f), Wout[o2], acc);
  out[row] = acc;
}

// ---------------- launcher ----------------
extern "C" void kernel_launch(void* const* d_in, const int* in_sizes, int n_in,
                              void* d_out, int out_size, void* d_ws, size_t ws_size,
                              hipStream_t stream) {
  (void)in_sizes; (void)n_in; (void)out_size; (void)ws_size;
  const int*   x        = (const int*)  d_in[0];
  const float* emb_rate = (const float*)d_in[1];
  const float* W_genre  = (const float*)d_in[2];
  const float* W_dir    = (const float*)d_in[3];
  const float* W_actor  = (const float*)d_in[4];
  const float* emb_gen  = (const float*)d_in[5];
  const float* emb_age  = (const float*)d_in[6];
  const float* emb_occ  = (const float*)d_in[7];
  const float* emb_area = (const float*)d_in[8];
  const float* W1   = (const float*)d_in[9];
  const float* b1   = (const float*)d_in[10];
  const float* W2   = (const float*)d_in[11];
  const float* b2   = (const float*)d_in[12];
  const float* Wout = (const float*)d_in[13];
  const float* bout = (const float*)d_in[14];
  float* outp = (float*)d_out;

  float* ws   = (float*)d_ws;
  float* pout = ws;                                   // 6*33*16384 floats
  u32*   bits = (u32*)(ws + POUT_F);                  // 16384*320 u32 = 21 MB
  u16*   Bf   = (u16*)(bits + BITS_U32);              // 646 KB, 16B-aligned
  float* P    = (float*)(Bf + BF_U16);
  float* W2t  = P + PTAB_F;

  prep_bf<<<(NSLOT*128 + 255)/256, 256, 0, stream>>>(W_genre, W_dir, W_actor, Bf);
  prep_p<<<(PTAB_F + 255)/256, 256, 0, stream>>>(emb_rate, emb_gen, emb_age, emb_occ,
                                                 emb_area, W1, P);
  prep_w2t<<<16, 256, 0, stream>>>(W2, W2t);

  pack<<<NROW/4, 256, 0, stream>>>(x, bits);

  dim3 gm(NROW/128, 4);
  kmain<<<gm, 256, 0, stream>>>(bits, Bf, pout);
  k2<<<NROW/64, 64, 0, stream>>>(x, pout, W_actor, P, W1, b1, W2t, b2, Wout, bout, outp);
}

// Round 10
// 350.945 us; speedup vs baseline: 1.0064x; 1.0064x over previous
//
#include <hip/hip_runtime.h>

#define NROW 16384
#define ROWI 10246
#define NSLICE 10                 // 0=G, 1=D(q0), 2=D(q1), 3=A(q1), 4..9=A(MODE2 y)
#define POUT_F (NSLICE*33*16384)
#define NSLOT 323                 // B slots: 0..319 tiles, 321=D@t0, 322=A@t69
#define BF_U16 ((size_t)NSLOT*128*8)
#define BITS_W 320                // u32 words per row: 10240 cols / 32
#define BITS_U32 ((size_t)NROW*BITS_W)
#define PTAB_ROWS 3438
#define PTAB_F (PTAB_ROWS*64)

typedef unsigned int u32;
typedef unsigned long long u64;
typedef unsigned short u16;
typedef short short8 __attribute__((ext_vector_type(8)));
typedef float f32x4 __attribute__((ext_vector_type(4)));

union AFrag { u32 u[4]; short8 s; };
union BFrag { uint4 v; short8 s; };

// ---------------- prep: B fragment table (bf16, MFMA layout) ----------------
__global__ void prep_bf(const float* __restrict__ Wg, const float* __restrict__ Wd,
                        const float* __restrict__ Wa, u16* __restrict__ Bf) {
  int id = blockIdx.x*256 + threadIdx.x;
  if (id >= NSLOT*128) return;
  int lane = id & 63, f = (id >> 6) & 1, slot = id >> 7;
  int t   = (slot == 321) ? 0 : (slot == 322) ? 69 : slot;
  int seg = (slot == 0) ? 0 : (slot <= 69) ? 1 : (slot <= 320) ? 2
            : (slot == 321) ? 1 : 2;                  // 0=G,1=D,2=A
  int clo = (seg == 0) ? 1  : (seg == 1) ? 26   : 2212;
  int chi = (seg == 0) ? 26 : (seg == 1) ? 2212 : 10242;
  int d  = f*16 + (lane & 15);
  int kb = t*32 + (lane >> 4)*8;
  u16 o[8];
  #pragma unroll
  for (int e = 0; e < 8; ++e) {
    int c = kb + e;
    float v = 0.f;
    if (c >= clo && c < chi) {
      if (seg == 0)      v = Wg[d*25   + (c-1)];
      else if (seg == 1) v = Wd[d*2186 + (c-26)];
      else               v = Wa[d*8030 + (c-2212)];
    }
    u32 bits = __float_as_uint(v);                    // RNE float->bf16
    o[e] = (u16)((bits + 0x7FFFu + ((bits >> 16) & 1u)) >> 16);
  }
  uint4 w;
  w.x = (u32)o[0] | ((u32)o[1] << 16);
  w.y = (u32)o[2] | ((u32)o[3] << 16);
  w.z = (u32)o[4] | ((u32)o[5] << 16);
  w.w = (u32)o[6] | ((u32)o[7] << 16);
  *(uint4*)&Bf[(size_t)id*8] = w;
}

// ---------------- prep: folded index-embedding table ----------------
__global__ void prep_p(const float* __restrict__ er, const float* __restrict__ eg,
                       const float* __restrict__ ea, const float* __restrict__ eo,
                       const float* __restrict__ ez, const float* __restrict__ W1,
                       float* __restrict__ P) {
  int id = blockIdx.x*256 + threadIdx.x;
  if (id >= PTAB_F) return;
  int r = id >> 6, o = id & 63;
  const float* emb; int woff;
  if (r < 6)       { emb = er + r*32;       woff = 0;   }
  else if (r < 8)  { emb = eg + (r-6)*32;   woff = 128; }
  else if (r < 15) { emb = ea + (r-8)*32;   woff = 160; }
  else if (r < 36) { emb = eo + (r-15)*32;  woff = 192; }
  else             { emb = ez + (r-36)*32;  woff = 224; }
  const float* w = W1 + o*256 + woff;
  float s = 0.f;
  #pragma unroll
  for (int c2 = 0; c2 < 32; ++c2) s += emb[c2]*w[c2];
  P[id] = s;
}

__global__ void prep_w2t(const float* __restrict__ W2, float* __restrict__ W2t) {
  int id = blockIdx.x*256 + threadIdx.x;
  if (id >= 64*64) return;
  int o = id >> 6, o2 = id & 63;
  W2t[o*64 + o2] = W2[o2*64 + o];
}

// ---------------- pack: linear-stream x -> bit matrix + side ints ----------
__global__ __launch_bounds__(256) void pack(const int* __restrict__ x,
                                            u32* __restrict__ bits,
                                            int* __restrict__ side) {
  const int lane = threadIdx.x & 63;
  const int row  = blockIdx.x*4 + (threadIdx.x >> 6);
  const int* base = x + (size_t)row*ROWI;
  u32* obase = bits + (size_t)row*BITS_W;
  #pragma unroll
  for (int g = 0; g < 5; ++g) {
    u32 keep = 0;
    #pragma unroll
    for (int ib = 0; ib < 2; ++ib) {
      int v[16];
      #pragma unroll
      for (int k = 0; k < 16; ++k)
        v[k] = base[g*2048 + (ib*16 + k)*64 + lane];
      #pragma unroll
      for (int k = 0; k < 16; ++k) {
        const int i = ib*16 + k;
        const u64 b = __ballot(v[k] != 0);
        keep = (lane == 2*i)     ? (u32)b         : keep;
        keep = (lane == 2*i + 1) ? (u32)(b >> 32) : keep;
      }
    }
    obase[g*64 + lane] = keep;
  }
  // side[row][0..6] = {rate, x10240, x10241, gender, age, occ, area}
  if (lane < 7) {
    const int v = (lane == 0) ? base[0] : base[10239 + lane];
    side[row*8 + lane] = v;
  }
}

// ---------------- fused MFMA bag kernel (A from bit matrix) ----------------
// Wave = 32 rows (2 row-sets of 16); block = 4 waves = 128 rows.
// MODE 0: tiles [0,40): t0 special (G + masked-D 321), rest D. slices S->0, T->1.
// MODE 1: tiles [40,80): t69 special (D + masked-A 322). S=D->2, T=A->3.
// MODE 2: tiles [80+40*y, +40): pure A -> slice 4+y.
template<int MODE>
__global__ __launch_bounds__(256, 2) void kmain(
    const u32* __restrict__ bits, const u16* __restrict__ Bf, float* __restrict__ pout) {
  const int lane = threadIdx.x & 63;
  const int wv   = threadIdx.x >> 6;
  const int row0w = blockIdx.x*128 + wv*32;
  const int r = lane & 15, g = lane >> 4, g8 = g*8;

  const int tb   = (MODE == 0) ? 0 : (MODE == 1) ? 40 : (80 + 40*blockIdx.y);
  const int tmax = tb + 39;

  const u32*   pW0 = bits + (size_t)(row0w + r)*BITS_W;
  const u32*   pW1 = bits + (size_t)(row0w + 16 + r)*BITS_W;
  const uint4* pB  = (const uint4*)Bf + lane;          // + (t*2+f)*64

  f32x4 z = {0.f,0.f,0.f,0.f};
  f32x4 S00=z,S01=z,S10=z,S11=z, T00=z,T01=z,T10=z,T11=z;
  int cS0=0,cS1=0,cT0=0,cT1=0;

  // bit words: current / next group (4 tiles each)
  uint4 Wc0 = *(const uint4*)&pW0[tb],   Wc1 = *(const uint4*)&pW1[tb];
  uint4 Wn0 = *(const uint4*)&pW0[tb+4], Wn1 = *(const uint4*)&pW1[tb+4];
  // B ring: 4 tiles staged, reload +4
  uint4 B000 = pB[((tb+0)*2)*64], B001 = pB[((tb+0)*2+1)*64];
  uint4 B010 = pB[((tb+1)*2)*64], B011 = pB[((tb+1)*2+1)*64];
  uint4 B100 = pB[((tb+2)*2)*64], B101 = pB[((tb+2)*2+1)*64];
  uint4 B110 = pB[((tb+3)*2)*64], B111 = pB[((tb+3)*2+1)*64];

#define BUILD_AF(AF, BYTE)                                                      \
    AF.u[0] = __umul24(((BYTE)      & 1u) + ((((BYTE) >> 1) & 1u) << 16), 0x3F80u); \
    AF.u[1] = __umul24((((BYTE)>>2) & 1u) + ((((BYTE) >> 3) & 1u) << 16), 0x3F80u); \
    AF.u[2] = __umul24((((BYTE)>>4) & 1u) + ((((BYTE) >> 5) & 1u) << 16), 0x3F80u); \
    AF.u[3] = __umul24((((BYTE)>>6) & 1u) + ((((BYTE) >> 7) & 1u) << 16), 0x3F80u);

#define MFMA4(P, B0, B1, AF0, AF1)                                             \
    P##00 = __builtin_amdgcn_mfma_f32_16x16x32_bf16(AF0.s, B0.s, P##00,0,0,0); \
    P##01 = __builtin_amdgcn_mfma_f32_16x16x32_bf16(AF0.s, B1.s, P##01,0,0,0); \
    P##10 = __builtin_amdgcn_mfma_f32_16x16x32_bf16(AF1.s, B0.s, P##10,0,0,0); \
    P##11 = __builtin_amdgcn_mfma_f32_16x16x32_bf16(AF1.s, B1.s, P##11,0,0,0);

#define TILE(ACC, SP, CMP, TT) do {                                            \
    const u32 by0 = (Wc0.CMP >> g8) & 0xFFu;                                   \
    const u32 by1 = (Wc1.CMP >> g8) & 0xFFu;                                   \
    AFrag a0, a1; BUILD_AF(a0, by0); BUILD_AF(a1, by1);                        \
    BFrag b0, b1; b0.v = B##SP##0; b1.v = B##SP##1;                            \
    MFMA4(ACC, b0, b1, a0, a1);                                                \
    c##ACC##0 += __popc(by0); c##ACC##1 += __popc(by1);                        \
    { int tn = (TT) + 4; if (tn > tmax) tn = tmax;                             \
      B##SP##0 = pB[(tn*2)*64]; B##SP##1 = pB[(tn*2+1)*64]; }                  \
  } while (0)

#define TILE0 do {                                                             \
    const u32 by0 = (Wc0.x >> g8) & 0xFFu;                                     \
    const u32 by1 = (Wc1.x >> g8) & 0xFFu;                                     \
    AFrag a0, a1; BUILD_AF(a0, by0); BUILD_AF(a1, by1);                        \
    BFrag b0, b1; b0.v = B000; b1.v = B001;                                    \
    MFMA4(S, b0, b1, a0, a1);                                                  \
    { BFrag e0, e1; e0.v = pB[(321*2)*64]; e1.v = pB[(321*2+1)*64];            \
      MFMA4(T, e0, e1, a0, a1); }                                              \
    _Pragma("unroll")                                                          \
    for (int j = 0; j < 4; ++j) {                                              \
      const int c0 = g8 + 2*j, c1 = c0 + 1;                                    \
      const int u0 = (by0>>(2*j))&1, u1 = (by0>>(2*j+1))&1;                    \
      const int v0 = (by1>>(2*j))&1, v1 = (by1>>(2*j+1))&1;                    \
      if (c0 >= 1 && c0 < 26) { cS0 += u0; cS1 += v0; }                        \
      else if (c0 >= 26)      { cT0 += u0; cT1 += v0; }                        \
      if (c1 < 26) { cS0 += u1; cS1 += v1; } else { cT0 += u1; cT1 += v1; }    \
    }                                                                          \
    B000 = pB[(4*2)*64]; B001 = pB[(4*2+1)*64];                                \
  } while (0)

#define TILE69 do {                                                            \
    const u32 by0 = (Wc0.y >> g8) & 0xFFu;                                     \
    const u32 by1 = (Wc1.y >> g8) & 0xFFu;                                     \
    AFrag a0, a1; BUILD_AF(a0, by0); BUILD_AF(a1, by1);                        \
    BFrag b0, b1; b0.v = B010; b1.v = B011;                                    \
    MFMA4(S, b0, b1, a0, a1);                                                  \
    { BFrag e0, e1; e0.v = pB[(322*2)*64]; e1.v = pB[(322*2+1)*64];            \
      MFMA4(T, e0, e1, a0, a1); }                                              \
    _Pragma("unroll")                                                          \
    for (int j = 0; j < 4; ++j) {                                              \
      const int s0 = ((by0>>(2*j))&1) + ((by0>>(2*j+1))&1);                    \
      const int s1 = ((by1>>(2*j))&1) + ((by1>>(2*j+1))&1);                    \
      if (j < 2) { if (g == 0) { cS0 += s0; cS1 += s1; }                       \
                   else        { cT0 += s0; cT1 += s1; } }                     \
      else       { cT0 += s0; cT1 += s1; }                                     \
    }                                                                          \
    B010 = pB[(73*2)*64]; B011 = pB[(73*2+1)*64];                              \
  } while (0)

#define ROTW(T4) do { Wc0 = Wn0; Wc1 = Wn1;                                    \
    int nb = (T4) + 8; if (nb > tb + 36) nb = tb + 36;                         \
    Wn0 = *(const uint4*)&pW0[nb]; Wn1 = *(const uint4*)&pW1[nb]; } while (0)

  if constexpr (MODE == 0) {
    for (int i = 0; i < 10; ++i) {
      const int t4 = 4*i;
      if (i == 0) { TILE0;            TILE(T,01,y,1);    TILE(T,10,z,2);    TILE(T,11,w,3); }
      else        { TILE(T,00,x,t4);  TILE(T,01,y,t4+1); TILE(T,10,z,t4+2); TILE(T,11,w,t4+3); }
      ROTW(t4);
    }
  } else if constexpr (MODE == 1) {
    for (int i = 0; i < 10; ++i) {
      const int t4 = 40 + 4*i;
      if (i < 7)       { TILE(S,00,x,t4);  TILE(S,01,y,t4+1); TILE(S,10,z,t4+2); TILE(S,11,w,t4+3); }
      else if (i == 7) { TILE(S,00,x,68);  TILE69;            TILE(T,10,z,70);   TILE(T,11,w,71); }
      else             { TILE(T,00,x,t4);  TILE(T,01,y,t4+1); TILE(T,10,z,t4+2); TILE(T,11,w,t4+3); }
      ROTW(t4);
    }
  } else {
    for (int i = 0; i < 10; ++i) {
      const int t4 = tb + 4*i;
      TILE(S,00,x,t4); TILE(S,01,y,t4+1); TILE(S,10,z,t4+2); TILE(S,11,w,t4+3);
      ROTW(t4);
    }
  }

  cS0 += __shfl_xor(cS0,16); cS0 += __shfl_xor(cS0,32);
  cS1 += __shfl_xor(cS1,16); cS1 += __shfl_xor(cS1,32);
  cT0 += __shfl_xor(cT0,16); cT0 += __shfl_xor(cT0,32);
  cT1 += __shfl_xor(cT1,16); cT1 += __shfl_xor(cT1,32);

#define STO4(P, SL) do { float* bp = pout + (size_t)(SL)*33*16384;             \
    _Pragma("unroll")                                                          \
    for (int q2 = 0; q2 < 4; ++q2) {                                           \
      bp[(size_t)r*16384      + row0w + g*4 + q2]      = P##00[q2];            \
      bp[(size_t)(16+r)*16384 + row0w + g*4 + q2]      = P##01[q2];            \
      bp[(size_t)r*16384      + row0w + 16 + g*4 + q2] = P##10[q2];            \
      bp[(size_t)(16+r)*16384 + row0w + 16 + g*4 + q2] = P##11[q2];            \
    } } while (0)
#define STOC(SL, C0, C1) do { if (lane < 16) {                                 \
    pout[((size_t)(SL)*33 + 32)*16384 + row0w + lane]      = (float)(C0);      \
    pout[((size_t)(SL)*33 + 32)*16384 + row0w + 16 + lane] = (float)(C1); } } while (0)

  if constexpr (MODE == 0) {
    STO4(S, 0); STOC(0, cS0, cS1);
    STO4(T, 1); STOC(1, cT0, cT1);
  } else if constexpr (MODE == 1) {
    STO4(S, 2); STOC(2, cS0, cS1);
    STO4(T, 3); STOC(3, cT0, cT1);
  } else {
    const int sl = 4 + blockIdx.y;
    STO4(S, sl); STOC(sl, cS0, cS1);
  }
#undef STO4
#undef STOC
#undef ROTW
#undef TILE69
#undef TILE0
#undef TILE
#undef MFMA4
#undef BUILD_AF
}

// ---------------- reduce + tail + MLP kernel ----------------
__global__ __launch_bounds__(64, 1) void k2(
    const int* __restrict__ side, const float* __restrict__ pout,
    const float* __restrict__ Wa, const float* __restrict__ P,
    const float* __restrict__ W1, const float* __restrict__ b1,
    const float* __restrict__ W2t, const float* __restrict__ b2,
    const float* __restrict__ Wout, const float* __restrict__ bout,
    float* __restrict__ out) {
  const int row = blockIdx.x*64 + threadIdx.x;
  const int4 s0 = *(const int4*)&side[row*8];      // rate, x10240, x10241, gender
  const int4 s1 = *(const int4*)&side[row*8 + 4];  // age, occ, area, (pad)

#define PSL(SL, D) pout[(size_t)((SL)*33 + (D))*16384 + row]
  float mG[32], mD[32], mA[32];
  #pragma unroll
  for (int d = 0; d < 32; ++d) {
    mG[d] = PSL(0, d);
    mD[d] = PSL(1, d) + PSL(2, d);
    float s = 0.f;
    #pragma unroll
    for (int k = 3; k < 10; ++k) s += PSL(k, d);
    mA[d] = s;
  }
  float cG = PSL(0, 32);
  float cD = PSL(1, 32) + PSL(2, 32);
  float cA = 0.f;
  #pragma unroll
  for (int k = 3; k < 10; ++k) cA += PSL(k, 32);
#undef PSL

  // tail actor columns 10240, 10241 (= Wa cols 8028, 8029)
  {
    const float t0 = (float)s0.y, t1 = (float)s0.z;
    cA += t0 + t1;
    #pragma unroll
    for (int d = 0; d < 32; ++d)
      mA[d] = fmaf(t1, Wa[d*8030 + 8029], fmaf(t0, Wa[d*8030 + 8028], mA[d]));
  }

  #pragma unroll
  for (int d = 0; d < 32; ++d) { mG[d] /= cG; mD[d] /= cD; mA[d] /= cA; }

  const int ridx = s0.x;
  const int gi = s0.w, ai = s1.x, oi = s1.y, ari = s1.z;
  const float* Pr = P + (size_t)ridx*64;
  const float* Pg = P + (size_t)(6 + gi)*64;
  const float* Pa = P + (size_t)(8 + ai)*64;
  const float* Po = P + (size_t)(15 + oi)*64;
  const float* Pz = P + (size_t)(36 + ari)*64;

  float h1[64];
  #pragma unroll
  for (int o = 0; o < 64; ++o)
    h1[o] = b1[o] + ((Pr[o] + Pg[o]) + (Pa[o] + Po[o])) + Pz[o];

  #pragma unroll
  for (int o = 0; o < 64; ++o) {
    const float* w = W1 + o*256;
    float a = h1[o];
    #pragma unroll
    for (int d = 0; d < 32; ++d) a = fmaf(mG[d], w[32+d], a);
    #pragma unroll
    for (int d = 0; d < 32; ++d) a = fmaf(mD[d], w[64+d], a);
    #pragma unroll
    for (int d = 0; d < 32; ++d) a = fmaf(mA[d], w[96+d], a);
    h1[o] = fmaxf(a, 0.f);
  }

  float h2[64];
  #pragma unroll
  for (int o2 = 0; o2 < 64; ++o2) h2[o2] = b2[o2];
  #pragma unroll
  for (int o = 0; o < 64; ++o) {
    const float h = h1[o];
    const float* wr = W2t + o*64;
    #pragma unroll
    for (int o2 = 0; o2 < 64; ++o2) h2[o2] = fmaf(h, wr[o2], h2[o2]);
  }
  float acc = bout[0];
  #pragma unroll
  for (int o2 = 0; o2 < 64; ++o2) acc = fmaf(fmaxf(h2[o2], 0.f), Wout[o2], acc);
  out[row] = acc;
}

// ---------------- launcher ----------------
extern "C" void kernel_launch(void* const* d_in, const int* in_sizes, int n_in,
                              void* d_out, int out_size, void* d_ws, size_t ws_size,
                              hipStream_t stream) {
  (void)in_sizes; (void)n_in; (void)out_size; (void)ws_size;
  const int*   x        = (const int*)  d_in[0];
  const float* emb_rate = (const float*)d_in[1];
  const float* W_genre  = (const float*)d_in[2];
  const float* W_dir    = (const float*)d_in[3];
  const float* W_actor  = (const float*)d_in[4];
  const float* emb_gen  = (const float*)d_in[5];
  const float* emb_age  = (const float*)d_in[6];
  const float* emb_occ  = (const float*)d_in[7];
  const float* emb_area = (const float*)d_in[8];
  const float* W1   = (const float*)d_in[9];
  const float* b1   = (const float*)d_in[10];
  const float* W2   = (const float*)d_in[11];
  const float* b2   = (const float*)d_in[12];
  const float* Wout = (const float*)d_in[13];
  const float* bout = (const float*)d_in[14];
  float* outp = (float*)d_out;

  float* ws   = (float*)d_ws;
  float* pout = ws;                                   // 10*33*16384 floats
  u32*   bits = (u32*)(ws + POUT_F);                  // 21 MB
  u16*   Bf   = (u16*)(bits + BITS_U32);              // 646 KB, 16B-aligned
  float* P    = (float*)(Bf + BF_U16);
  float* W2t  = P + PTAB_F;
  int*   side = (int*)(W2t + 64*64);                  // 16384*8 ints

  prep_bf<<<(NSLOT*128 + 255)/256, 256, 0, stream>>>(W_genre, W_dir, W_actor, Bf);
  prep_p<<<(PTAB_F + 255)/256, 256, 0, stream>>>(emb_rate, emb_gen, emb_age, emb_occ,
                                                 emb_area, W1, P);
  prep_w2t<<<16, 256, 0, stream>>>(W2, W2t);

  pack<<<NROW/4, 256, 0, stream>>>(x, bits, side);

  dim3 gA(NROW/128, 6);
  kmain<2><<<gA, 256, 0, stream>>>(bits, Bf, pout);
  kmain<0><<<NROW/128, 256, 0, stream>>>(bits, Bf, pout);
  kmain<1><<<NROW/128, 256, 0, stream>>>(bits, Bf, pout);

  k2<<<NROW/64, 64, 0, stream>>>(side, pout, W_actor, P, W1, b1, W2t, b2, Wout, bout, outp);
}

// Round 11
// 279.550 us; speedup vs baseline: 1.2635x; 1.2554x over previous
//
#include <hip/hip_runtime.h>

#define NROW 16384
#define ROWI 10246
#define POUT_F (3*33*16384)       // slices: 0=G, 1=D, 2=A
#define NSLOT 323                 // B slots: 0..319 tiles, 321=D@t0, 322=A@t69
#define BF_U16 ((size_t)NSLOT*128*8)
#define PTAB_ROWS 3438
#define PTAB_F (PTAB_ROWS*64)

typedef unsigned int u32;
typedef unsigned long long u64;
typedef unsigned short u16;
typedef short short8 __attribute__((ext_vector_type(8)));
typedef float f32x4 __attribute__((ext_vector_type(4)));

union AFrag { u32 u[4]; short8 s; };
union BFrag { uint4 v; short8 s; };

// ---------------- prep: B fragment table (bf16, MFMA layout) ----------------
// Frag id = (slot*2 + f)*64 + lane ; elem e: k = t*32 + (lane>>4)*8 + e,
// d = f*16 + (lane&15). Masked to the slot's segment (zeros elsewhere).
__global__ void prep_bf(const float* __restrict__ Wg, const float* __restrict__ Wd,
                        const float* __restrict__ Wa, u16* __restrict__ Bf) {
  int id = blockIdx.x*256 + threadIdx.x;
  if (id >= NSLOT*128) return;
  int lane = id & 63, f = (id >> 6) & 1, slot = id >> 7;
  int t   = (slot == 321) ? 0 : (slot == 322) ? 69 : slot;
  int seg = (slot == 0) ? 0 : (slot <= 69) ? 1 : (slot <= 320) ? 2
            : (slot == 321) ? 1 : 2;                  // 0=G,1=D,2=A
  int clo = (seg == 0) ? 1  : (seg == 1) ? 26   : 2212;
  int chi = (seg == 0) ? 26 : (seg == 1) ? 2212 : 10242;
  int d  = f*16 + (lane & 15);
  int kb = t*32 + (lane >> 4)*8;
  u16 o[8];
  #pragma unroll
  for (int e = 0; e < 8; ++e) {
    int c = kb + e;
    float v = 0.f;
    if (c >= clo && c < chi) {
      if (seg == 0)      v = Wg[d*25   + (c-1)];
      else if (seg == 1) v = Wd[d*2186 + (c-26)];
      else               v = Wa[d*8030 + (c-2212)];
    }
    u32 bits = __float_as_uint(v);                    // RNE float->bf16
    o[e] = (u16)((bits + 0x7FFFu + ((bits >> 16) & 1u)) >> 16);
  }
  uint4 w;
  w.x = (u32)o[0] | ((u32)o[1] << 16);
  w.y = (u32)o[2] | ((u32)o[3] << 16);
  w.z = (u32)o[4] | ((u32)o[5] << 16);
  w.w = (u32)o[6] | ((u32)o[7] << 16);
  *(uint4*)&Bf[(size_t)id*8] = w;
}

// ---------------- prep: folded index-embedding table ----------------
__global__ void prep_p(const float* __restrict__ er, const float* __restrict__ eg,
                       const float* __restrict__ ea, const float* __restrict__ eo,
                       const float* __restrict__ ez, const float* __restrict__ W1,
                       float* __restrict__ P) {
  int id = blockIdx.x*256 + threadIdx.x;
  if (id >= PTAB_F) return;
  int r = id >> 6, o = id & 63;
  const float* emb; int woff;
  if (r < 6)       { emb = er + r*32;       woff = 0;   }
  else if (r < 8)  { emb = eg + (r-6)*32;   woff = 128; }
  else if (r < 15) { emb = ea + (r-8)*32;   woff = 160; }
  else if (r < 36) { emb = eo + (r-15)*32;  woff = 192; }
  else             { emb = ez + (r-36)*32;  woff = 224; }
  const float* w = W1 + o*256 + woff;
  float s = 0.f;
  #pragma unroll
  for (int c2 = 0; c2 < 32; ++c2) s += emb[c2]*w[c2];
  P[id] = s;
}

__global__ void prep_w2t(const float* __restrict__ W2, float* __restrict__ W2t) {
  int id = blockIdx.x*256 + threadIdx.x;
  if (id >= 64*64) return;
  int o = id >> 6, o2 = id & 63;
  W2t[o*64 + o2] = W2[o2*64 + o];
}

// ---------------- fused pack + MFMA + combine kernel ----------------
// Block = 256 thr (4 waves) = 32 rows. Phase 1: pack rows -> LDS bits (ballot).
// Phase 2: wave (s=wv&1 row-set of 16, h=wv>>1 K-half of 160 tiles) MFMA.
// Phase 2.5: merge halves in LDS, write pout[3][33][16384].
__global__ __launch_bounds__(256, 2) void fusedK(
    const int* __restrict__ x, const u16* __restrict__ Bf,
    float* __restrict__ pout, int* __restrict__ side) {
  __shared__ u32 bitsL[32*324];        // [row][word], stride 324 (320 used)
  __shared__ float poutL[4][33][32];   // slots: 0=G(h0),1=D(h0),2=A(h0),3=A(h1)

  const int lane = threadIdx.x & 63;
  const int wv   = threadIdx.x >> 6;
  const int row0 = blockIdx.x * 32;
  const int r = lane & 15, g = lane >> 4, g8 = g*8;

  // ---- phase 1: each wave packs 8 rows (linear coalesced reads, 32-deep) ----
  for (int i8 = 0; i8 < 8; ++i8) {
    const int rL = wv*8 + i8;
    const int* base = x + (size_t)(row0 + rL)*ROWI;
    #pragma unroll
    for (int gg = 0; gg < 5; ++gg) {
      int v[32];
      #pragma unroll
      for (int k = 0; k < 32; ++k) v[k] = base[gg*2048 + k*64 + lane];
      u32 keep = 0;
      #pragma unroll
      for (int k = 0; k < 32; ++k) {
        const u64 b = __ballot(v[k] != 0);
        keep = (lane == 2*k)     ? (u32)b         : keep;
        keep = (lane == 2*k + 1) ? (u32)(b >> 32) : keep;
      }
      bitsL[rL*324 + gg*64 + lane] = keep;   // word w = cols [32w, 32w+32)
    }
  }
  {
    const int i2 = lane >> 3, j = lane & 7;
    if (j < 7) {
      const int* bp = x + (size_t)(row0 + wv*8 + i2)*ROWI;
      side[(row0 + wv*8 + i2)*8 + j] = (j == 0) ? bp[0] : bp[10239 + j];
    }
  }
  __syncthreads();

  // ---- phase 2 ----
  const int s16 = (wv & 1) * 16;
  const bool h0 = (wv >> 1) == 0;
  const int tb = h0 ? 0 : 160;
  const int tmax = tb + 159;
  const u32* brow = &bitsL[(s16 + r)*324];
  const uint4* pB = (const uint4*)Bf + lane;   // + (t*2+f)*64

  f32x4 z = {0.f,0.f,0.f,0.f};
  f32x4 G0=z,G1=z,D0=z,D1=z,A0=z,A1=z;
  int cG=0,cD=0,cA=0;

  uint4 B00 = pB[((tb+0)*2)*64], B01 = pB[((tb+0)*2+1)*64];
  uint4 B10 = pB[((tb+1)*2)*64], B11 = pB[((tb+1)*2+1)*64];
  uint4 B20 = pB[((tb+2)*2)*64], B21 = pB[((tb+2)*2+1)*64];
  uint4 B30 = pB[((tb+3)*2)*64], B31 = pB[((tb+3)*2+1)*64];

#define MFMA_(AF, B, ACC) __builtin_amdgcn_mfma_f32_16x16x32_bf16((AF).s, (B).s, ACC, 0,0,0)

#define TILEW(J, T) do {                                                       \
    const int t = (T);                                                         \
    const u32 byte = (W4##J >> g8) & 0xFFu;                                    \
    AFrag af;                                                                  \
    af.u[0] = __umul24((byte & 1u)    + (((byte>>1)&1u)<<16), 0x3F80u);        \
    af.u[1] = __umul24(((byte>>2)&1u) + (((byte>>3)&1u)<<16), 0x3F80u);        \
    af.u[2] = __umul24(((byte>>4)&1u) + (((byte>>5)&1u)<<16), 0x3F80u);        \
    af.u[3] = __umul24(((byte>>6)&1u) + (((byte>>7)&1u)<<16), 0x3F80u);        \
    BFrag b0, b1; b0.v = B##J##0; b1.v = B##J##1;                              \
    if (!h0) {                                                                 \
      A0 = MFMA_(af,b0,A0); A1 = MFMA_(af,b1,A1); cA += __popc(byte);          \
    } else if (t == 0) {                                                       \
      G0 = MFMA_(af,b0,G0); G1 = MFMA_(af,b1,G1);                              \
      BFrag e0,e1; e0.v = pB[(321*2)*64]; e1.v = pB[(321*2+1)*64];             \
      D0 = MFMA_(af,e0,D0); D1 = MFMA_(af,e1,D1);                              \
      _Pragma("unroll")                                                        \
      for (int jj = 0; jj < 4; ++jj) {                                         \
        const int c0 = g8 + 2*jj, c1 = c0 + 1;                                 \
        const int u0 = (byte>>(2*jj))&1, u1 = (byte>>(2*jj+1))&1;              \
        if (c0 >= 1 && c0 < 26) cG += u0; else if (c0 >= 26) cD += u0;         \
        if (c1 < 26) cG += u1; else cD += u1;                                  \
      }                                                                        \
    } else if (t == 69) {                                                      \
      D0 = MFMA_(af,b0,D0); D1 = MFMA_(af,b1,D1);                              \
      BFrag e0,e1; e0.v = pB[(322*2)*64]; e1.v = pB[(322*2+1)*64];             \
      A0 = MFMA_(af,e0,A0); A1 = MFMA_(af,e1,A1);                              \
      _Pragma("unroll")                                                        \
      for (int jj = 0; jj < 4; ++jj) {                                         \
        const int s01 = ((byte>>(2*jj))&1) + ((byte>>(2*jj+1))&1);             \
        if (jj < 2) { if (g == 0) cD += s01; else cA += s01; }                 \
        else cA += s01;                                                        \
      }                                                                        \
    } else if (t < 69) {                                                       \
      D0 = MFMA_(af,b0,D0); D1 = MFMA_(af,b1,D1); cD += __popc(byte);          \
    } else {                                                                   \
      A0 = MFMA_(af,b0,A0); A1 = MFMA_(af,b1,A1); cA += __popc(byte);          \
    }                                                                          \
    int tn = t + 4; if (tn > tmax) tn = tmax;                                  \
    B##J##0 = pB[(tn*2)*64]; B##J##1 = pB[(tn*2+1)*64];                        \
  } while (0)

  for (int i = 0; i < 40; ++i) {
    const int t0 = tb + 4*i;
    const uint4 W4u = *(const uint4*)&brow[t0];    // ds_read_b128: 4 tiles
    const u32 W40 = W4u.x, W41 = W4u.y, W42 = W4u.z, W43 = W4u.w;
    TILEW(0, t0); TILEW(1, t0+1); TILEW(2, t0+2); TILEW(3, t0+3);
  }
#undef TILEW

  cG += __shfl_xor(cG,16); cG += __shfl_xor(cG,32);
  cD += __shfl_xor(cD,16); cD += __shfl_xor(cD,32);
  cA += __shfl_xor(cA,16); cA += __shfl_xor(cA,32);

#define STOF(ACC0, ACC1, SLOT) do {                                            \
    *(f32x4*)&poutL[SLOT][r][s16 + 4*g]    = ACC0;                             \
    *(f32x4*)&poutL[SLOT][16+r][s16 + 4*g] = ACC1; } while (0)

  if (h0) {
    STOF(G0,G1,0); STOF(D0,D1,1); STOF(A0,A1,2);
    if (lane < 16) {
      poutL[0][32][s16+lane] = (float)cG;
      poutL[1][32][s16+lane] = (float)cD;
      poutL[2][32][s16+lane] = (float)cA;
    }
  } else {
    STOF(A0,A1,3);
    if (lane < 16) poutL[3][32][s16+lane] = (float)cA;
  }
#undef STOF
  __syncthreads();

  // ---- phase 2.5: merge halves, write global pout ----
  for (int id = threadIdx.x; id < 3*33*32; id += 256) {
    const int seg = id / (33*32);
    const int rem = id - seg*(33*32);
    const int d = rem >> 5, row = rem & 31;
    float v = poutL[seg][d][row];
    if (seg == 2) v += poutL[3][d][row];
    pout[((size_t)seg*33 + d)*16384 + row0 + row] = v;
  }
}

// ---------------- reduce + tail + MLP kernel ----------------
__global__ __launch_bounds__(64, 1) void k2(
    const int* __restrict__ side, const float* __restrict__ pout,
    const float* __restrict__ Wa, const float* __restrict__ P,
    const float* __restrict__ W1, const float* __restrict__ b1,
    const float* __restrict__ W2t, const float* __restrict__ b2,
    const float* __restrict__ Wout, const float* __restrict__ bout,
    float* __restrict__ out) {
  const int row = blockIdx.x*64 + threadIdx.x;
  const int4 s0 = *(const int4*)&side[row*8];      // rate, x10240, x10241, gender
  const int4 s1 = *(const int4*)&side[row*8 + 4];  // age, occ, area, (pad)

#define PSL(SL, D) pout[(size_t)((SL)*33 + (D))*16384 + row]
  float mG[32], mD[32], mA[32];
  #pragma unroll
  for (int d = 0; d < 32; ++d) {
    mG[d] = PSL(0, d);
    mD[d] = PSL(1, d);
    mA[d] = PSL(2, d);
  }
  float cG = PSL(0, 32);
  float cD = PSL(1, 32);
  float cA = PSL(2, 32);
#undef PSL

  // tail actor columns 10240, 10241 (= Wa cols 8028, 8029)
  {
    const float t0 = (float)s0.y, t1 = (float)s0.z;
    cA += t0 + t1;
    #pragma unroll
    for (int d = 0; d < 32; ++d)
      mA[d] = fmaf(t1, Wa[d*8030 + 8029], fmaf(t0, Wa[d*8030 + 8028], mA[d]));
  }

  #pragma unroll
  for (int d = 0; d < 32; ++d) { mG[d] /= cG; mD[d] /= cD; mA[d] /= cA; }

  const int ridx = s0.x;
  const int gi = s0.w, ai = s1.x, oi = s1.y, ari = s1.z;
  const float* Pr = P + (size_t)ridx*64;
  const float* Pg = P + (size_t)(6 + gi)*64;
  const float* Pa = P + (size_t)(8 + ai)*64;
  const float* Po = P + (size_t)(15 + oi)*64;
  const float* Pz = P + (size_t)(36 + ari)*64;

  float h1[64];
  #pragma unroll
  for (int o = 0; o < 64; ++o)
    h1[o] = b1[o] + ((Pr[o] + Pg[o]) + (Pa[o] + Po[o])) + Pz[o];

  #pragma unroll
  for (int o = 0; o < 64; ++o) {
    const float* w = W1 + o*256;
    float a = h1[o];
    #pragma unroll
    for (int d = 0; d < 32; ++d) a = fmaf(mG[d], w[32+d], a);
    #pragma unroll
    for (int d = 0; d < 32; ++d) a = fmaf(mD[d], w[64+d], a);
    #pragma unroll
    for (int d = 0; d < 32; ++d) a = fmaf(mA[d], w[96+d], a);
    h1[o] = fmaxf(a, 0.f);
  }

  float h2[64];
  #pragma unroll
  for (int o2 = 0; o2 < 64; ++o2) h2[o2] = b2[o2];
  #pragma unroll
  for (int o = 0; o < 64; ++o) {
    const float h = h1[o];
    const float* wr = W2t + o*64;
    #pragma unroll
    for (int o2 = 0; o2 < 64; ++o2) h2[o2] = fmaf(h, wr[o2], h2[o2]);
  }
  float acc = bout[0];
  #pragma unroll
  for (int o2 = 0; o2 < 64; ++o2) acc = fmaf(fmaxf(h2[o2], 0.f), Wout[o2], acc);
  out[row] = acc;
}

// ---------------- launcher ----------------
extern "C" void kernel_launch(void* const* d_in, const int* in_sizes, int n_in,
                              void* d_out, int out_size, void* d_ws, size_t ws_size,
                              hipStream_t stream) {
  (void)in_sizes; (void)n_in; (void)out_size; (void)ws_size;
  const int*   x        = (const int*)  d_in[0];
  const float* emb_rate = (const float*)d_in[1];
  const float* W_genre  = (const float*)d_in[2];
  const float* W_dir    = (const float*)d_in[3];
  const float* W_actor  = (const float*)d_in[4];
  const float* emb_gen  = (const float*)d_in[5];
  const float* emb_age  = (const float*)d_in[6];
  const float* emb_occ  = (const float*)d_in[7];
  const float* emb_area = (const float*)d_in[8];
  const float* W1   = (const float*)d_in[9];
  const float* b1   = (const float*)d_in[10];
  const float* W2   = (const float*)d_in[11];
  const float* b2   = (const float*)d_in[12];
  const float* Wout = (const float*)d_in[13];
  const float* bout = (const float*)d_in[14];
  float* outp = (float*)d_out;

  float* ws   = (float*)d_ws;
  float* pout = ws;                                   // 3*33*16384 floats
  u16*   Bf   = (u16*)(ws + POUT_F);                  // 646 KB, 16B-aligned
  float* P    = (float*)(Bf + BF_U16);
  float* W2t  = P + PTAB_F;
  int*   side = (int*)(W2t + 64*64);                  // 16384*8 ints

  prep_bf<<<(NSLOT*128 + 255)/256, 256, 0, stream>>>(W_genre, W_dir, W_actor, Bf);
  prep_p<<<(PTAB_F + 255)/256, 256, 0, stream>>>(emb_rate, emb_gen, emb_age, emb_occ,
                                                 emb_area, W1, P);
  prep_w2t<<<16, 256, 0, stream>>>(W2, W2t);

  fusedK<<<NROW/32, 256, 0, stream>>>(x, Bf, pout, side);

  k2<<<NROW/64, 64, 0, stream>>>(side, pout, W_actor, P, W1, b1, W2t, b2, Wout, bout, outp);
}